// Round 2
// baseline (275.480 us; speedup 1.0000x reference)
//
#include <hip/hip_runtime.h>

#define B_   2
#define SQ_  2048
#define SK_  512
#define HID_ 1024
#define NH_  16
#define HD_  64

typedef __bf16 bf16x8 __attribute__((ext_vector_type(8)));
typedef float  f32x4  __attribute__((ext_vector_type(4)));

__device__ inline unsigned short f2bf(float f) {
    unsigned u = __builtin_bit_cast(unsigned, f);
    u += 0x7fffu + ((u >> 16) & 1u);   // round-to-nearest-even
    return (unsigned short)(u >> 16);
}

// ---------------- fp32 -> bf16 conversion ----------------
__global__ __launch_bounds__(256) void cvt_kernel(const float* __restrict__ src,
                                                  unsigned short* __restrict__ dst, int n) {
    int i = (blockIdx.x * 256 + threadIdx.x) * 4;
    if (i >= n) return;
    float4 v = *reinterpret_cast<const float4*>(src + i);
    ushort4 o;
    o.x = f2bf(v.x); o.y = f2bf(v.y); o.z = f2bf(v.z); o.w = f2bf(v.w);
    *reinterpret_cast<ushort4*>(dst + i) = o;
}

__global__ __launch_bounds__(256) void cvt3_kernel(const float* __restrict__ s0,
                                                   const float* __restrict__ s1,
                                                   const float* __restrict__ s2,
                                                   unsigned short* __restrict__ d0,
                                                   unsigned short* __restrict__ d1,
                                                   unsigned short* __restrict__ d2, int n) {
    const float* s = blockIdx.y == 0 ? s0 : (blockIdx.y == 1 ? s1 : s2);
    unsigned short* d = blockIdx.y == 0 ? d0 : (blockIdx.y == 1 ? d1 : d2);
    int i = (blockIdx.x * 256 + threadIdx.x) * 4;
    if (i >= n) return;
    float4 v = *reinterpret_cast<const float4*>(s + i);
    ushort4 o;
    o.x = f2bf(v.x); o.y = f2bf(v.y); o.z = f2bf(v.z); o.w = f2bf(v.w);
    *reinterpret_cast<ushort4*>(d + i) = o;
}

// ---------------- NT GEMM: C[m,n] = sum_k A[m,k]*B[n,k], K=1024 ----------------
// Output stored bf16 in head-split layout [b, h, s, d] (h = n>>6, d = n&63).
#define LDT 40   // padded LDS stride (bf16 elems); 80 B, 16B-aligned

__global__ __launch_bounds__(256, 2) void gemm_nt(const unsigned short* __restrict__ A,
                                                  const unsigned short* __restrict__ Bm,
                                                  unsigned short* __restrict__ outp,
                                                  int slenShift) {
    __shared__ unsigned short as[128 * LDT];
    __shared__ unsigned short bs[128 * LDT];
    const int K = 1024;
    const int Slen = 1 << slenShift;

    int n0 = blockIdx.x * 128;
    int m0 = blockIdx.y * 128;
    int tid  = threadIdx.x;
    int lane = tid & 63;
    int w    = tid >> 6;
    int quad = lane >> 4;
    int lc   = lane & 15;
    int wr = (w >> 1) * 64;
    int wc = (w & 1) * 64;

    f32x4 zero4 = {0.f, 0.f, 0.f, 0.f};
    f32x4 acc[4][4];
#pragma unroll
    for (int i = 0; i < 4; i++)
#pragma unroll
        for (int j = 0; j < 4; j++) acc[i][j] = zero4;

    for (int k0 = 0; k0 < K; k0 += 32) {
#pragma unroll
        for (int i = 0; i < 2; i++) {
            int c = tid + i * 256;
            int row = c >> 2, kg = c & 3;
            *reinterpret_cast<uint4*>(&as[row * LDT + kg * 8]) =
                *reinterpret_cast<const uint4*>(A + (size_t)(m0 + row) * K + k0 + kg * 8);
            *reinterpret_cast<uint4*>(&bs[row * LDT + kg * 8]) =
                *reinterpret_cast<const uint4*>(Bm + (size_t)(n0 + row) * K + k0 + kg * 8);
        }
        __syncthreads();
        bf16x8 af[4], bfr[4];
#pragma unroll
        for (int mt = 0; mt < 4; mt++)
            af[mt] = *reinterpret_cast<const bf16x8*>(&as[(wr + mt * 16 + lc) * LDT + quad * 8]);
#pragma unroll
        for (int nt = 0; nt < 4; nt++)
            bfr[nt] = *reinterpret_cast<const bf16x8*>(&bs[(wc + nt * 16 + lc) * LDT + quad * 8]);
#pragma unroll
        for (int mt = 0; mt < 4; mt++)
#pragma unroll
            for (int nt = 0; nt < 4; nt++)
                acc[mt][nt] = __builtin_amdgcn_mfma_f32_16x16x32_bf16(af[mt], bfr[nt], acc[mt][nt], 0, 0, 0);
        __syncthreads();
    }

    // epilogue: permuted bf16 store to [b, h, s, d]
#pragma unroll
    for (int mt = 0; mt < 4; mt++) {
#pragma unroll
        for (int nt = 0; nt < 4; nt++) {
            int n = n0 + wc + nt * 16 + lc;
            int h = n >> 6, d = n & 63;
#pragma unroll
            for (int r = 0; r < 4; r++) {
                int m = m0 + wr + mt * 16 + quad * 4 + r;
                int b = m >> slenShift;
                int s = m & (Slen - 1);
                size_t off = (((size_t)(b * NH_ + h)) * Slen + s) * HD_ + d;
                outp[off] = f2bf(acc[mt][nt][r]);
            }
        }
    }
}

// ---------------- fused attention ----------------
// grid: B*NH*(SQ/64) blocks, 256 threads (4 waves). wave w owns q-rows [16w,16w+16).
#define LQT 72   // padded LDS stride (bf16), 144 B, 16B-aligned

__global__ __launch_bounds__(256, 2) void attn_kernel(const unsigned short* __restrict__ qh,
                                                      const unsigned short* __restrict__ kh,
                                                      const unsigned short* __restrict__ vh,
                                                      const int* __restrict__ maskp,
                                                      float* __restrict__ octx,
                                                      float* __restrict__ oscores) {
    __shared__ unsigned short qs[64 * LQT];
    __shared__ unsigned short ks[64 * LQT];
    __shared__ unsigned short vts[64 * LQT];  // v transposed: [d][s_local]
    __shared__ unsigned short ps[64 * LQT];   // probs chunk:  [qrow][s_local]
    __shared__ float lm[SK_];

    int bid = blockIdx.x;
    int qt = bid & 31;
    int h  = (bid >> 5) & 15;
    int b  = bid >> 9;

    int tid  = threadIdx.x;
    int lane = tid & 63;
    int w    = tid >> 6;
    int quad = lane >> 4;
    int lc   = lane & 15;
    int wrow = w * 16;

    const unsigned short* qp = qh + ((size_t)(b * NH_ + h) * SQ_ + qt * 64) * HD_;
    const unsigned short* kp = kh + ((size_t)(b * NH_ + h) * SK_) * HD_;
    const unsigned short* vp = vh + ((size_t)(b * NH_ + h) * SK_) * HD_;

    // stage q tile [64][64]
#pragma unroll
    for (int i = 0; i < 2; i++) {
        int c = tid + i * 256;
        int row = c >> 3, kg = c & 7;
        *reinterpret_cast<uint4*>(&qs[row * LQT + kg * 8]) =
            *reinterpret_cast<const uint4*>(qp + row * HD_ + kg * 8);
    }
    // stage additive mask
#pragma unroll
    for (int i = 0; i < 2; i++) {
        int c = tid + i * 256;
        lm[c] = maskp[b * SK_ + c] ? 0.0f : -3.0e38f;
    }

    f32x4 zero4 = {0.f, 0.f, 0.f, 0.f};
    f32x4 sacc[32];
#pragma unroll
    for (int t = 0; t < 32; t++) sacc[t] = zero4;

    float* srowp = oscores + ((size_t)(b * NH_ + h) * SQ_ + qt * 64) * SK_;

    // ---- S = q k^T / 8, store scores (unmasked) ----
    for (int kt = 0; kt < 8; kt++) {
#pragma unroll
        for (int i = 0; i < 2; i++) {
            int c = tid + i * 256;
            int row = c >> 3, kg = c & 7;
            *reinterpret_cast<uint4*>(&ks[row * LQT + kg * 8]) =
                *reinterpret_cast<const uint4*>(kp + (kt * 64 + row) * HD_ + kg * 8);
        }
        __syncthreads();
        bf16x8 qf0 = *reinterpret_cast<const bf16x8*>(&qs[(wrow + lc) * LQT + quad * 8]);
        bf16x8 qf1 = *reinterpret_cast<const bf16x8*>(&qs[(wrow + lc) * LQT + 32 + quad * 8]);
#pragma unroll
        for (int tl = 0; tl < 4; tl++) {
            int t = kt * 4 + tl;
            bf16x8 kf0 = *reinterpret_cast<const bf16x8*>(&ks[(tl * 16 + lc) * LQT + quad * 8]);
            sacc[t] = __builtin_amdgcn_mfma_f32_16x16x32_bf16(qf0, kf0, sacc[t], 0, 0, 0);
            bf16x8 kf1 = *reinterpret_cast<const bf16x8*>(&ks[(tl * 16 + lc) * LQT + 32 + quad * 8]);
            sacc[t] = __builtin_amdgcn_mfma_f32_16x16x32_bf16(qf1, kf1, sacc[t], 0, 0, 0);
        }
        // scale + store scores for the 4 finished tiles
#pragma unroll
        for (int tl = 0; tl < 4; tl++) {
            int t = kt * 4 + tl;
#pragma unroll
            for (int r = 0; r < 4; r++) {
                float sv = sacc[t][r] * 0.125f;
                sacc[t][r] = sv;
                int row = wrow + quad * 4 + r;
                int col = t * 16 + lc;
                srowp[(size_t)row * SK_ + col] = sv;
            }
        }
        __syncthreads();
    }

    // ---- softmax over 512 cols (row lives in one 16-lane quad group) ----
#pragma unroll
    for (int t = 0; t < 32; t++) {
        float add = lm[t * 16 + lc];
#pragma unroll
        for (int r = 0; r < 4; r++) sacc[t][r] += add;
    }
#pragma unroll
    for (int r = 0; r < 4; r++) {
        float m = -3.4e38f;
#pragma unroll
        for (int t = 0; t < 32; t++) m = fmaxf(m, sacc[t][r]);
        m = fmaxf(m, __shfl_xor(m, 1));
        m = fmaxf(m, __shfl_xor(m, 2));
        m = fmaxf(m, __shfl_xor(m, 4));
        m = fmaxf(m, __shfl_xor(m, 8));
        float sum = 0.f;
#pragma unroll
        for (int t = 0; t < 32; t++) {
            float e = __expf(sacc[t][r] - m);
            sacc[t][r] = e;
            sum += e;
        }
        sum += __shfl_xor(sum, 1);
        sum += __shfl_xor(sum, 2);
        sum += __shfl_xor(sum, 4);
        sum += __shfl_xor(sum, 8);
        float inv = 1.0f / sum;
#pragma unroll
        for (int t = 0; t < 32; t++) sacc[t][r] *= inv;
    }

    // ---- context = P @ V ----
    f32x4 cacc[4];
#pragma unroll
    for (int ct = 0; ct < 4; ct++) cacc[ct] = zero4;

    for (int kt = 0; kt < 8; kt++) {
        // write P chunk (C-layout -> LDS row-major; wave writes/reads only its own 16 rows)
#pragma unroll
        for (int tl = 0; tl < 4; tl++) {
            int t = kt * 4 + tl;
#pragma unroll
            for (int r = 0; r < 4; r++)
                ps[(wrow + quad * 4 + r) * LQT + tl * 16 + lc] = f2bf(sacc[t][r]);
        }
        // stage v tile transposed: vts[d][sv]
#pragma unroll
        for (int i = 0; i < 2; i++) {
            int c = tid + i * 256;
            int sv = c >> 3, dg = c & 7;
            uint4 vv = *reinterpret_cast<const uint4*>(vp + (kt * 64 + sv) * HD_ + dg * 8);
            const unsigned short* e = reinterpret_cast<const unsigned short*>(&vv);
#pragma unroll
            for (int j = 0; j < 8; j++)
                vts[(dg * 8 + j) * LQT + sv] = e[j];
        }
        __syncthreads();
#pragma unroll
        for (int ks2 = 0; ks2 < 2; ks2++) {
            bf16x8 af = *reinterpret_cast<const bf16x8*>(&ps[(wrow + lc) * LQT + ks2 * 32 + quad * 8]);
#pragma unroll
            for (int ct = 0; ct < 4; ct++) {
                bf16x8 bv = *reinterpret_cast<const bf16x8*>(&vts[(ct * 16 + lc) * LQT + ks2 * 32 + quad * 8]);
                cacc[ct] = __builtin_amdgcn_mfma_f32_16x16x32_bf16(af, bv, cacc[ct], 0, 0, 0);
            }
        }
        __syncthreads();
    }

    // context store: [b, s, h*64+d] fp32
#pragma unroll
    for (int ct = 0; ct < 4; ct++) {
        int d = ct * 16 + lc;
#pragma unroll
        for (int r = 0; r < 4; r++) {
            int s = qt * 64 + wrow + quad * 4 + r;
            octx[((size_t)b * SQ_ + s) * HID_ + h * HD_ + d] = cacc[ct][r];
        }
    }
}

// ---------------- launch ----------------
extern "C" void kernel_launch(void* const* d_in, const int* in_sizes, int n_in,
                              void* d_out, int out_size, void* d_ws, size_t ws_size,
                              hipStream_t stream) {
    const float* hs   = (const float*)d_in[0];
    const float* enc  = (const float*)d_in[1];
    const int*   mask = (const int*)d_in[2];
    const float* Wq   = (const float*)d_in[3];
    const float* Wk   = (const float*)d_in[4];
    const float* Wv   = (const float*)d_in[5];
    float* out = (float*)d_out;

    unsigned short* hb  = (unsigned short*)d_ws;      // hidden bf16   (4194304)
    unsigned short* eb  = hb  + 4194304;              // encoder bf16  (1048576)
    unsigned short* wqb = eb  + 1048576;
    unsigned short* wkb = wqb + 1048576;
    unsigned short* wvb = wkb + 1048576;
    unsigned short* qhp = wvb + 1048576;              // q [b,h,s,d] bf16 (4194304)
    unsigned short* khp = qhp + 4194304;              // k [b,h,s,d] bf16 (1048576)
    unsigned short* vhp = khp + 1048576;              // v [b,h,s,d] bf16 (1048576)

    cvt_kernel<<<4096, 256, 0, stream>>>(hs, hb, 4194304);
    cvt_kernel<<<1024, 256, 0, stream>>>(enc, eb, 1048576);
    cvt3_kernel<<<dim3(1024, 3), 256, 0, stream>>>(Wq, Wk, Wv, wqb, wkb, wvb, 1048576);

    gemm_nt<<<dim3(8, 32), 256, 0, stream>>>(hb, wqb, qhp, 11);  // M=4096, Slen=2048
    gemm_nt<<<dim3(8, 8),  256, 0, stream>>>(eb, wkb, khp, 9);   // M=1024, Slen=512
    gemm_nt<<<dim3(8, 8),  256, 0, stream>>>(eb, wvb, vhp, 9);

    attn_kernel<<<1024, 256, 0, stream>>>(qhp, khp, vhp, mask, out, out + 4194304);
}

// Round 3
// 228.203 us; speedup vs baseline: 1.2072x; 1.2072x over previous
//
#include <hip/hip_runtime.h>

#define B_   2
#define SQ_  2048
#define SK_  512
#define HID_ 1024
#define NH_  16
#define HD_  64

typedef __bf16 bf16x8 __attribute__((ext_vector_type(8)));
typedef float  f32x4  __attribute__((ext_vector_type(4)));

__device__ __forceinline__ unsigned short f2bf(float f) {
    unsigned u = __builtin_bit_cast(unsigned, f);
    u += 0x7fffu + ((u >> 16) & 1u);   // round-to-nearest-even
    return (unsigned short)(u >> 16);
}

// async global->LDS, 16B per lane, lands at lds_base + lane*16
__device__ __forceinline__ void gll16(const unsigned short* g, unsigned short* l) {
    __builtin_amdgcn_global_load_lds(
        (const __attribute__((address_space(1))) unsigned int*)(const void*)g,
        (__attribute__((address_space(3))) unsigned int*)(void*)l,
        16, 0, 0);
}

// ---------------- fused fp32 -> bf16 conversion (all 5 tensors) ----------------
__global__ __launch_bounds__(256) void cvt_all(const float* __restrict__ hs,
                                               const float* __restrict__ enc,
                                               const float* __restrict__ wq,
                                               const float* __restrict__ wk,
                                               const float* __restrict__ wv,
                                               unsigned short* __restrict__ hb,
                                               unsigned short* __restrict__ eb,
                                               unsigned short* __restrict__ wqb,
                                               unsigned short* __restrict__ wkb,
                                               unsigned short* __restrict__ wvb) {
    size_t i = ((size_t)blockIdx.x * 256 + threadIdx.x) * 4;
    const float* s; unsigned short* d; size_t off;
    if (i < 4194304)      { s = hs;  d = hb;  off = i; }
    else if (i < 5242880) { s = enc; d = eb;  off = i - 4194304; }
    else if (i < 6291456) { s = wq;  d = wqb; off = i - 5242880; }
    else if (i < 7340032) { s = wk;  d = wkb; off = i - 6291456; }
    else                  { s = wv;  d = wvb; off = i - 7340032; }
    float4 v = *reinterpret_cast<const float4*>(s + off);
    ushort4 o;
    o.x = f2bf(v.x); o.y = f2bf(v.y); o.z = f2bf(v.z); o.w = f2bf(v.w);
    *reinterpret_cast<ushort4*>(d + off) = o;
}

// ---------------- fused QKV NT GEMM ----------------
// 64x128 tiles, BK=32, global_load_lds staging, XOR-swizzled LDS chunks.
// grid 768 = 96 m-superblocks x 8 n-blocks (n fastest for A-tile L2 reuse).
// ms 0..63: Q (A=hb, W=wq) -> qo [b,h,s,d]
// ms 64..79: K (A=eb, W=wk) -> ko [b,h,s,d]
// ms 80..95: V (A=eb, W=wv) -> vo [b,h,d,s]  (pre-transposed for attention)
__global__ __launch_bounds__(256, 4) void gemm_qkv(const unsigned short* __restrict__ hb,
                                                   const unsigned short* __restrict__ eb,
                                                   const unsigned short* __restrict__ wq,
                                                   const unsigned short* __restrict__ wk,
                                                   const unsigned short* __restrict__ wv,
                                                   unsigned short* __restrict__ qo,
                                                   unsigned short* __restrict__ ko,
                                                   unsigned short* __restrict__ vo) {
    __shared__ unsigned short as[64 * 32];    // [row][32 k] rows of 64B, swizzled chunks
    __shared__ unsigned short bs[128 * 32];

    int bid = blockIdx.x;
    int nb = bid & 7, ms = bid >> 3;
    const unsigned short* Ab; const unsigned short* Wb;
    int mrow, mode;
    if (ms < 64)      { mode = 0; Ab = hb; Wb = wq; mrow = ms * 64; }
    else if (ms < 80) { mode = 1; Ab = eb; Wb = wk; mrow = (ms - 64) * 64; }
    else              { mode = 2; Ab = eb; Wb = wv; mrow = (ms - 80) * 64; }
    int n0 = nb * 128;

    int tid = threadIdx.x, lane = tid & 63, w = tid >> 6;
    int quad = lane >> 4, lc = lane & 15;

    // loader lane mapping: row-in-16 = lane>>2, slot = lane&3, fetched logical chunk = slot ^ ((lane>>3)&3)
    int lrow = lane >> 2;
    int chA  = (lane & 3) ^ ((lane >> 3) & 3);
    const unsigned short* agp  = Ab + (size_t)(mrow + w * 16 + lrow) * 1024 + chA * 8;
    const unsigned short* bgp0 = Wb + (size_t)(n0 + w * 32 + lrow) * 1024 + chA * 8;
    const unsigned short* bgp1 = bgp0 + (size_t)16 * 1024;
    unsigned short* asl  = &as[(w * 16) * 32];
    unsigned short* bsl0 = &bs[(w * 32) * 32];
    unsigned short* bsl1 = &bs[(w * 32 + 16) * 32];

    f32x4 zero4 = {0.f, 0.f, 0.f, 0.f};
    f32x4 acc[4][2];
#pragma unroll
    for (int i = 0; i < 4; i++) { acc[i][0] = zero4; acc[i][1] = zero4; }

    int rsw = (lc >> 1) & 3;   // reader swizzle
    for (int k0 = 0; k0 < 1024; k0 += 32) {
        gll16(agp + k0, asl);
        gll16(bgp0 + k0, bsl0);
        gll16(bgp1 + k0, bsl1);
        __syncthreads();
        bf16x8 af[4], bfr[2];
#pragma unroll
        for (int mt = 0; mt < 4; mt++)
            af[mt] = *reinterpret_cast<const bf16x8*>(&as[(mt * 16 + lc) * 32 + (quad ^ rsw) * 8]);
#pragma unroll
        for (int nt = 0; nt < 2; nt++)
            bfr[nt] = *reinterpret_cast<const bf16x8*>(&bs[(w * 32 + nt * 16 + lc) * 32 + (quad ^ rsw) * 8]);
#pragma unroll
        for (int mt = 0; mt < 4; mt++)
#pragma unroll
            for (int nt = 0; nt < 2; nt++)
                acc[mt][nt] = __builtin_amdgcn_mfma_f32_16x16x32_bf16(af[mt], bfr[nt], acc[mt][nt], 0, 0, 0);
        __syncthreads();
    }

#pragma unroll
    for (int mt = 0; mt < 4; mt++) {
#pragma unroll
        for (int nt = 0; nt < 2; nt++) {
            int n = n0 + w * 32 + nt * 16 + lc;
            int h = n >> 6, d = n & 63;
#pragma unroll
            for (int r = 0; r < 4; r++) {
                int M = mrow + mt * 16 + quad * 4 + r;
                unsigned short val = f2bf(acc[mt][nt][r]);
                if (mode == 0) {
                    int b = M >> 11, s = M & 2047;
                    qo[(((size_t)(b * NH_ + h)) * SQ_ + s) * HD_ + d] = val;
                } else if (mode == 1) {
                    int b = M >> 9, s = M & 511;
                    ko[(((size_t)(b * NH_ + h)) * SK_ + s) * HD_ + d] = val;
                } else {
                    int b = M >> 9, s = M & 511;
                    vo[(((size_t)(b * NH_ + h)) * HD_ + d) * SK_ + s] = val;
                }
            }
        }
    }
}

// ---------------- fused attention ----------------
// grid B*NH*(SQ/64) = 1024 blocks, 4 waves; wave w owns q-rows [16w,16w+16).
// Computes S^T per tile (A=K,B=Q) so lane holds q-row=lc, k-cols quad*4+r ->
// coalesced float4 score stores + cheap row softmax.
#define PST 72   // ps stride (shorts): 144B, conflict-free 2-way

__global__ __launch_bounds__(256, 2) void attn_kernel(const unsigned short* __restrict__ qh,
                                                      const unsigned short* __restrict__ kh,
                                                      const unsigned short* __restrict__ vh,
                                                      const int* __restrict__ maskp,
                                                      float* __restrict__ octx,
                                                      float* __restrict__ oscores) {
    __shared__ unsigned short qs[64 * 64];
    __shared__ unsigned short ks[64 * 64];
    __shared__ unsigned short vts[64 * 64];   // V^T tile: [d][s_local]
    __shared__ unsigned short ps[64 * PST];   // P chunk: [qrow][s_local], padded
    __shared__ float lm[SK_];

    int bid = blockIdx.x;
    int qt = bid & 31;
    int h  = (bid >> 5) & 15;
    int b  = bid >> 9;

    int tid = threadIdx.x, lane = tid & 63, w = tid >> 6;
    int quad = lane >> 4, lc = lane & 15;
    int wrow = w * 16;

    const unsigned short* qp = qh + ((size_t)(b * NH_ + h) * SQ_ + qt * 64) * HD_;
    const unsigned short* kp = kh + ((size_t)(b * NH_ + h) * SK_) * HD_;
    const unsigned short* vp = vh + ((size_t)(b * NH_ + h) * HD_) * SK_;  // [d][s]

    // loader mapping for 128B-row tiles: row-in-8 = lane>>3, slot = lane&7,
    // fetched logical chunk = slot ^ (lane>>3)
    int lr  = lane >> 3;
    int chg = (lane & 7) ^ lr;

    // stage q tile (8 wave-instructions, 2 per wave)
#pragma unroll
    for (int j = 0; j < 2; j++) {
        int c = w * 2 + j;
        gll16(qp + (c * 8 + lr) * 64 + chg * 8, &qs[c * 512]);
    }
    // stage additive mask
#pragma unroll
    for (int i = 0; i < 2; i++) {
        int c = tid + i * 256;
        lm[c] = maskp[b * SK_ + c] ? 0.0f : -3.0e38f;
    }
    __syncthreads();

    int rsw = lc & 7;   // reader swizzle for 8-chunk rows
    bf16x8 qf[2];
#pragma unroll
    for (int hf = 0; hf < 2; hf++)
        qf[hf] = *reinterpret_cast<const bf16x8*>(&qs[(wrow + lc) * 64 + ((quad + hf * 4) ^ rsw) * 8]);

    f32x4 zero4 = {0.f, 0.f, 0.f, 0.f};
    f32x4 sacc[32];
#pragma unroll
    for (int t = 0; t < 32; t++) sacc[t] = zero4;

    float* srowp = oscores + ((size_t)(b * NH_ + h) * SQ_ + qt * 64) * SK_;

    // ---- S^T = (K q^T)/8 : store scores coalesced ----
    for (int kt = 0; kt < 8; kt++) {
#pragma unroll
        for (int j = 0; j < 2; j++) {
            int c = w * 2 + j;
            gll16(kp + (kt * 64 + c * 8 + lr) * 64 + chg * 8, &ks[c * 512]);
        }
        __syncthreads();
#pragma unroll
        for (int tl = 0; tl < 4; tl++) {
            int t = kt * 4 + tl;
#pragma unroll
            for (int hf = 0; hf < 2; hf++) {
                bf16x8 kf = *reinterpret_cast<const bf16x8*>(
                    &ks[(tl * 16 + lc) * 64 + ((quad + hf * 4) ^ rsw) * 8]);
                sacc[t] = __builtin_amdgcn_mfma_f32_16x16x32_bf16(kf, qf[hf], sacc[t], 0, 0, 0);
            }
        }
        // scale + coalesced store: lane holds q-row (wrow+lc), k-cols t*16+quad*4..+3
#pragma unroll
        for (int tl = 0; tl < 4; tl++) {
            int t = kt * 4 + tl;
            sacc[t] *= 0.125f;
            *reinterpret_cast<f32x4*>(&srowp[(size_t)(wrow + lc) * SK_ + t * 16 + quad * 4]) = sacc[t];
        }
        __syncthreads();
    }

    // ---- softmax over 512 k-cols (row replicated across the 4 quads) ----
#pragma unroll
    for (int t = 0; t < 32; t++) {
        float4 mv = *reinterpret_cast<const float4*>(&lm[t * 16 + quad * 4]);
        sacc[t][0] += mv.x; sacc[t][1] += mv.y; sacc[t][2] += mv.z; sacc[t][3] += mv.w;
    }
    float mx = -3.4e38f;
#pragma unroll
    for (int t = 0; t < 32; t++)
#pragma unroll
        for (int j = 0; j < 4; j++) mx = fmaxf(mx, sacc[t][j]);
    mx = fmaxf(mx, __shfl_xor(mx, 16));
    mx = fmaxf(mx, __shfl_xor(mx, 32));
    float sum = 0.f;
#pragma unroll
    for (int t = 0; t < 32; t++)
#pragma unroll
        for (int j = 0; j < 4; j++) {
            float e = __expf(sacc[t][j] - mx);
            sacc[t][j] = e;
            sum += e;
        }
    sum += __shfl_xor(sum, 16);
    sum += __shfl_xor(sum, 32);
    float inv = 1.0f / sum;
#pragma unroll
    for (int t = 0; t < 32; t++) sacc[t] *= inv;

    // ---- context = P @ V  (A=P rows=q, B=V^T rows=d) ----
    f32x4 cacc[4];
#pragma unroll
    for (int ct = 0; ct < 4; ct++) cacc[ct] = zero4;

    for (int kt = 0; kt < 8; kt++) {
        // write P chunk: lane's 4 probs -> ps[qrow][t*16+quad*4], b64, conflict-free
#pragma unroll
        for (int tl = 0; tl < 4; tl++) {
            int t = kt * 4 + tl;
            ushort4 pk;
            pk.x = f2bf(sacc[t][0]); pk.y = f2bf(sacc[t][1]);
            pk.z = f2bf(sacc[t][2]); pk.w = f2bf(sacc[t][3]);
            *reinterpret_cast<ushort4*>(&ps[(wrow + lc) * PST + tl * 16 + quad * 4]) = pk;
        }
        // stage V^T tile [d][s_local]
#pragma unroll
        for (int j = 0; j < 2; j++) {
            int c = w * 2 + j;
            gll16(vp + (size_t)(c * 8 + lr) * SK_ + kt * 64 + chg * 8, &vts[c * 512]);
        }
        __syncthreads();
#pragma unroll
        for (int ks2 = 0; ks2 < 2; ks2++) {
            bf16x8 af = *reinterpret_cast<const bf16x8*>(&ps[(wrow + lc) * PST + ks2 * 32 + quad * 8]);
#pragma unroll
            for (int ct = 0; ct < 4; ct++) {
                bf16x8 bv = *reinterpret_cast<const bf16x8*>(
                    &vts[(ct * 16 + lc) * 64 + ((quad + ks2 * 4) ^ rsw) * 8]);
                cacc[ct] = __builtin_amdgcn_mfma_f32_16x16x32_bf16(af, bv, cacc[ct], 0, 0, 0);
            }
        }
        __syncthreads();
    }

    // context store: [b, s, h*64+d] fp32 (C layout: row=q-in-16, col=d)
#pragma unroll
    for (int ct = 0; ct < 4; ct++) {
        int d = ct * 16 + lc;
#pragma unroll
        for (int r = 0; r < 4; r++) {
            int s = qt * 64 + wrow + quad * 4 + r;
            octx[((size_t)b * SQ_ + s) * HID_ + h * HD_ + d] = cacc[ct][r];
        }
    }
}

// ---------------- launch ----------------
extern "C" void kernel_launch(void* const* d_in, const int* in_sizes, int n_in,
                              void* d_out, int out_size, void* d_ws, size_t ws_size,
                              hipStream_t stream) {
    const float* hs   = (const float*)d_in[0];
    const float* enc  = (const float*)d_in[1];
    const int*   mask = (const int*)d_in[2];
    const float* Wq   = (const float*)d_in[3];
    const float* Wk   = (const float*)d_in[4];
    const float* Wv   = (const float*)d_in[5];
    float* out = (float*)d_out;

    unsigned short* hb  = (unsigned short*)d_ws;      // hidden bf16   (4194304)
    unsigned short* eb  = hb  + 4194304;              // encoder bf16  (1048576)
    unsigned short* wqb = eb  + 1048576;
    unsigned short* wkb = wqb + 1048576;
    unsigned short* wvb = wkb + 1048576;
    unsigned short* qhp = wvb + 1048576;              // q [b,h,s,d]   (4194304)
    unsigned short* khp = qhp + 4194304;              // k [b,h,s,d]   (1048576)
    unsigned short* vhp = khp + 1048576;              // v [b,h,d,s]   (1048576)

    cvt_all<<<8192, 256, 0, stream>>>(hs, enc, Wq, Wk, Wv, hb, eb, wqb, wkb, wvb);
    gemm_qkv<<<768, 256, 0, stream>>>(hb, eb, wqb, wkb, wvb, qhp, khp, vhp);
    attn_kernel<<<1024, 256, 0, stream>>>(qhp, khp, vhp, mask, out, out + 4194304);
}